// Round 1
// baseline (210.504 us; speedup 1.0000x reference)
//
#include <hip/hip_runtime.h>

// Problem constants (from reference setup_inputs):
//   x:        [B=16, Cin=128, N=8192] fp32
//   weights1: [Cin=128, Cout=128, modes1=2048] fp32
//   out:      [B=16, Cout=128, L=4097] fp32
//
// Math collapse (see analysis): the reference's recursive "RFHT" returns
// [sum(x), 0, ..., 0] for power-of-two lengths; the neg()-mixing then reduces
// to a plain channel matmul on the m=0 component only; the inverse transform
// of an impulse at 0 over odd length 4097 is again an impulse at 0.
// => out[b,o,n] = delta(n==0) * (1/4097) * sum_i (sum_n x[b,i,n]) * w[i,o,0]

#define NN    8192
#define BB    16
#define CIN   128
#define COUT  128
#define MODES 2048
#define LOUT  4097

// Kernel 1: S[r] = sum over 8192 of x-row r, r in [0, 2048). One block/row.
__global__ __launch_bounds__(256) void row_sum_kernel(const float* __restrict__ x,
                                                      float* __restrict__ S) {
    const int r = blockIdx.x;
    const float4* __restrict__ xp = (const float4*)(x + (size_t)r * NN);
    const int t = threadIdx.x;
    float acc = 0.f;
#pragma unroll
    for (int it = 0; it < 8; ++it) {   // 8 * 256 float4 = 8192 floats
        float4 v = xp[t + it * 256];
        acc += (v.x + v.y) + (v.z + v.w);
    }
#pragma unroll
    for (int off = 32; off > 0; off >>= 1)
        acc += __shfl_down(acc, off, 64);
    __shared__ float wsum[4];
    const int lane = t & 63, wid = t >> 6;
    if (lane == 0) wsum[wid] = acc;
    __syncthreads();
    if (t == 0) S[r] = (wsum[0] + wsum[1]) + (wsum[2] + wsum[3]);
}

// Kernel 2: zero the whole output. out_size = 16*128*4097 = 8390656 floats
// = 2097664 float4 = 8194 blocks * 256 threads * 1 float4. Exact cover.
__global__ __launch_bounds__(256) void zero_kernel(float4* __restrict__ out) {
    out[(size_t)blockIdx.x * 256 + threadIdx.x] = make_float4(0.f, 0.f, 0.f, 0.f);
}

// Kernel 3: out[(b*COUT+o)*LOUT] = (1/LOUT) * sum_i S[b*CIN+i] * w[(i*COUT+o)*MODES]
// One block per (b,o), 128 threads parallelize over i, shuffle+LDS reduce.
__global__ __launch_bounds__(128) void mix_kernel(const float* __restrict__ S,
                                                  const float* __restrict__ w,
                                                  float* __restrict__ out) {
    const int bo = blockIdx.x;          // bo = b*128 + o
    const int b = bo >> 7, o = bo & 127;
    const int i = threadIdx.x;
    float p = S[b * CIN + i] * w[((size_t)i * COUT + o) * MODES];
#pragma unroll
    for (int off = 32; off > 0; off >>= 1)
        p += __shfl_down(p, off, 64);
    __shared__ float wsum[2];
    if ((i & 63) == 0) wsum[i >> 6] = p;
    __syncthreads();
    if (i == 0)
        out[(size_t)bo * LOUT] = (wsum[0] + wsum[1]) * (1.0f / (float)LOUT);
}

extern "C" void kernel_launch(void* const* d_in, const int* in_sizes, int n_in,
                              void* d_out, int out_size, void* d_ws, size_t ws_size,
                              hipStream_t stream) {
    const float* x = (const float*)d_in[0];   // 16*128*8192
    const float* w = (const float*)d_in[1];   // 128*128*2048
    float* out = (float*)d_out;               // 16*128*4097
    float* S = (float*)d_ws;                  // 2048 floats of scratch

    row_sum_kernel<<<BB * CIN, 256, 0, stream>>>(x, S);
    zero_kernel<<<8194, 256, 0, stream>>>((float4*)out);
    mix_kernel<<<BB * COUT, 128, 0, stream>>>(S, w, out);
}

// Round 2
// 208.227 us; speedup vs baseline: 1.0109x; 1.0109x over previous
//
#include <hip/hip_runtime.h>

// Problem constants (from reference setup_inputs):
//   x:        [B=16, Cin=128, N=8192] fp32
//   weights1: [Cin=128, Cout=128, modes1=2048] fp32
//   out:      [B=16, Cout=128, L=4097] fp32
//
// Math collapse (verified R1, absmax 0.0): the reference's recursive "RFHT"
// returns [sum(x), 0, ..., 0] for power-of-two lengths; the neg()-mixing
// reduces to a plain channel matmul on the m=0 component; the inverse
// transform of an impulse at 0 over odd length 4097 is again an impulse at 0.
// => out[b,o,n] = delta(n==0) * (1/4097) * sum_i (sum_n x[b,i,n]) * w[i,o,0]
//
// R2 change: fuse the output zero-fill into the row-sum kernel so the
// 33.5 MB of zero WRITEs overlap the 64 MB of x READs (HBM duplex), and
// drop one graph node.

#define NN    8192
#define BB    16
#define CIN   128
#define COUT  128
#define MODES 2048
#define LOUT  4097

#define OUT_F4   2097664   // 16*128*4097 floats / 4 = 2,097,664 float4
#define GRID1    2048      // BB*CIN row-sum blocks
#define THREADS1 256
#define ZSTRIDE  (GRID1 * THREADS1)   // 524288 float4 per sweep

// Kernel 1: S[r] = sum over 8192 of x-row r, AND zero the whole output.
// One block per x-row (r in [0,2048)). Zero stores are issued before the
// reduction so they overlap the load latency.
__global__ __launch_bounds__(256) void sum_and_zero_kernel(const float* __restrict__ x,
                                                           float* __restrict__ S,
                                                           float4* __restrict__ out) {
    const int t = threadIdx.x;
    const int r = blockIdx.x;
    const int gid = r * THREADS1 + t;

    const float4* __restrict__ xp = (const float4*)(x + (size_t)r * NN);

    // Issue all 8 row loads first (independent), then zero-stores, then reduce.
    float4 v[8];
#pragma unroll
    for (int it = 0; it < 8; ++it) v[it] = xp[t + it * THREADS1];

    const float4 z = make_float4(0.f, 0.f, 0.f, 0.f);
#pragma unroll
    for (int i = 0; i < 4; ++i) out[gid + i * ZSTRIDE] = z;   // 4 full sweeps
    if (gid < OUT_F4 - 4 * ZSTRIDE) out[gid + 4 * ZSTRIDE] = z;  // remainder (512 float4)

    float acc = 0.f;
#pragma unroll
    for (int it = 0; it < 8; ++it) acc += (v[it].x + v[it].y) + (v[it].z + v[it].w);

#pragma unroll
    for (int off = 32; off > 0; off >>= 1)
        acc += __shfl_down(acc, off, 64);
    __shared__ float wsum[4];
    const int lane = t & 63, wid = t >> 6;
    if (lane == 0) wsum[wid] = acc;
    __syncthreads();
    if (t == 0) S[r] = (wsum[0] + wsum[1]) + (wsum[2] + wsum[3]);
}

// Kernel 2: out[(b*COUT+o)*LOUT] = (1/LOUT) * sum_i S[b*CIN+i] * w[(i*COUT+o)*MODES]
// One block per (b,o), 128 threads over i, shuffle+LDS reduce.
__global__ __launch_bounds__(128) void mix_kernel(const float* __restrict__ S,
                                                  const float* __restrict__ w,
                                                  float* __restrict__ out) {
    const int bo = blockIdx.x;          // bo = b*128 + o
    const int b = bo >> 7, o = bo & 127;
    const int i = threadIdx.x;
    float p = S[b * CIN + i] * w[((size_t)i * COUT + o) * MODES];
#pragma unroll
    for (int off = 32; off > 0; off >>= 1)
        p += __shfl_down(p, off, 64);
    __shared__ float wsum[2];
    if ((i & 63) == 0) wsum[i >> 6] = p;
    __syncthreads();
    if (i == 0)
        out[(size_t)bo * LOUT] = (wsum[0] + wsum[1]) * (1.0f / (float)LOUT);
}

extern "C" void kernel_launch(void* const* d_in, const int* in_sizes, int n_in,
                              void* d_out, int out_size, void* d_ws, size_t ws_size,
                              hipStream_t stream) {
    const float* x = (const float*)d_in[0];   // 16*128*8192
    const float* w = (const float*)d_in[1];   // 128*128*2048
    float* out = (float*)d_out;               // 16*128*4097
    float* S = (float*)d_ws;                  // 2048 floats of scratch

    sum_and_zero_kernel<<<GRID1, THREADS1, 0, stream>>>(x, S, (float4*)out);
    mix_kernel<<<BB * COUT, 128, 0, stream>>>(S, w, out);
}